// Round 12
// baseline (266.666 us; speedup 1.0000x reference)
//
#include <hip/hip_runtime.h>
#include <hip/hip_bf16.h>

typedef unsigned short u16;
typedef unsigned int u32;
typedef __attribute__((ext_vector_type(8))) short bf16x8;
typedef __attribute__((ext_vector_type(4))) float f32x4;
typedef __attribute__((ext_vector_type(2))) float f32x2;

#define NN 20000      // nodes
#define NE 320000     // edges
#define NG 128        // graphs
#define HD 128        // hidden
#define NH 4          // heads
#define KIN 74        // input features
#define KP0 96        // KIN padded to multiple of 32
#define BN_EPS 1e-5f
#define SCAN_B 20     // ceil(NN/1024)

__device__ __forceinline__ float bf2f(u16 v){ return __uint_as_float(((u32)v)<<16); }
__device__ __forceinline__ float bflo(u32 v){ return __uint_as_float(v<<16); }
__device__ __forceinline__ float bfhi(u32 v){ return __uint_as_float(v & 0xffff0000u); }
__device__ __forceinline__ u16 f2bf(float f){
    u32 u = __float_as_uint(f);
    return (u16)((u + 0x7fffu + ((u>>16)&1u)) >> 16);   // RNE
}
__device__ __forceinline__ u32 pack2(float a, float b){
    return (u32)f2bf(a) | ((u32)f2bf(b) << 16);
}

// ---- fused prep: bf16 conversions + zero counts + zero bnstat ---------------
#define PREP_S0 (NN*KP0)
#define PREP_S1 (NH*HD*KP0)
#define PREP_S2 (NH*HD*HD)
#define PREP_TOT (PREP_S0 + PREP_S1 + PREP_S2 + NN + 2048)
__global__ void k_prep(const float* __restrict__ h, const float* __restrict__ W0,
                       const float* __restrict__ Wr, u16* __restrict__ hb,
                       u16* __restrict__ wt0, u16* __restrict__ wt1,
                       int* __restrict__ counts, float* __restrict__ bnstat){
    int i = blockIdx.x*256 + threadIdx.x;
    if(i < PREP_S0){
        int n = i/KP0, k = i - n*KP0;
        hb[i] = (k < KIN) ? f2bf(h[n*KIN + k]) : (u16)0;
        return;
    }
    i -= PREP_S0;
    if(i < PREP_S1){                       // W0[h][k][c] -> wt0[h][c][KP0]
        int k = i % KP0; int c = (i/KP0) % HD; int hh = i/(KP0*HD);
        wt0[i] = (k < KIN) ? f2bf(W0[(hh*KIN + k)*HD + c]) : (u16)0;
        return;
    }
    i -= PREP_S1;
    if(i < PREP_S2){                       // Wr[h][k][c] -> wt1[h][c][HD]
        int k = i % HD; int c = (i/HD) % HD; int hh = i/(HD*HD);
        wt1[i] = f2bf(Wr[(hh*HD + k)*HD + c]);
        return;
    }
    i -= PREP_S2;
    if(i < NN){ counts[i] = 0; return; }
    i -= NN;
    if(i < 2048) bnstat[i] = 0.f;
}

// ---- CSR build -------------------------------------------------------------
__global__ void k_hist(const int* __restrict__ dst, int* __restrict__ counts){
    int e = blockIdx.x*256 + threadIdx.x;
    if(e < NE) atomicAdd(&counts[dst[e]], 1);
}

__global__ void k_scan1(const int* __restrict__ counts, int* __restrict__ rowptr,
                        int* __restrict__ tsum){
    __shared__ int wsum[16];
    int tx = threadIdx.x, lane = tx & 63, wid = tx >> 6;
    int i = blockIdx.x*1024 + tx;
    int v = (i < NN) ? counts[i] : 0;
    int s = v;
    #pragma unroll
    for(int d = 1; d < 64; d <<= 1){ int o = __shfl_up(s, d); if(lane >= d) s += o; }
    if(lane == 63) wsum[wid] = s;
    __syncthreads();
    int woff = 0, total = 0;
    #pragma unroll
    for(int w_ = 0; w_ < 16; ++w_){ int sw = wsum[w_]; total += sw; if(w_ < wid) woff += sw; }
    if(i < NN) rowptr[i] = woff + s - v;     // tile-local exclusive
    if(tx == 0) tsum[blockIdx.x] = total;
}

__global__ void k_scan3(int* __restrict__ rowptr, const int* __restrict__ tsum,
                        int* __restrict__ cursor){
    __shared__ int s_off;
    int tx = threadIdx.x;
    if(tx < 64){
        int v = (tx < SCAN_B && tx < (int)blockIdx.x) ? tsum[tx] : 0;
        #pragma unroll
        for(int d = 32; d > 0; d >>= 1) v += __shfl_xor(v, d);
        if(tx == 0) s_off = v;
    }
    __syncthreads();
    int i = blockIdx.x*1024 + tx;
    if(i < NN){
        int val = rowptr[i] + s_off;
        rowptr[i] = val;
        cursor[i] = val;
    }
    if(blockIdx.x == 0 && tx == 0) rowptr[NN] = NE;
}

__global__ void k_scatter(const int* __restrict__ src, const int* __restrict__ dst,
                          int* __restrict__ cursor, int* __restrict__ srcs){
    int e = blockIdx.x*256 + threadIdx.x;
    if(e >= NE) return;
    int d = dst[e];
    int p = atomicAdd(&cursor[d], 1);
    srcs[p] = src[e];
}

// ---- z = x @ W per head via MFMA; z layout [n][h][c] -----------------------
// grid (NN/32, NH), 256 threads = 4 waves.
// C/D mapping: col=lane&15 (channel r16), row=(lane>>4)*4+reg (node kg*4+reg).
template<int KP>
__global__ void k_gemm_mfma(const u16* __restrict__ xb, const u16* __restrict__ wt,
                            u16* __restrict__ z){
    int h = blockIdx.y;
    int tx = threadIdx.x, lane = tx & 63, w = tx >> 6;
    int n0 = blockIdx.x*32 + (w >> 1)*16;
    int c0 = (w & 1)*64;
    int r16 = lane & 15, kg = lane >> 4;
    const u16* ap = xb + (size_t)(n0 + r16)*KP + kg*8;
    const u16* bp = wt + ((size_t)h*HD + c0 + r16)*KP + kg*8;
    f32x4 acc0 = {0.f,0.f,0.f,0.f}, acc1 = {0.f,0.f,0.f,0.f};
    f32x4 acc2 = {0.f,0.f,0.f,0.f}, acc3 = {0.f,0.f,0.f,0.f};
    #pragma unroll
    for(int k0 = 0; k0 < KP; k0 += 32){
        bf16x8 av = *(const bf16x8*)(ap + k0);
        bf16x8 b0 = *(const bf16x8*)(bp + k0);
        bf16x8 b1 = *(const bf16x8*)(bp + 16*KP + k0);
        bf16x8 b2 = *(const bf16x8*)(bp + 32*KP + k0);
        bf16x8 b3 = *(const bf16x8*)(bp + 48*KP + k0);
        acc0 = __builtin_amdgcn_mfma_f32_16x16x32_bf16(av, b0, acc0, 0, 0, 0);
        acc1 = __builtin_amdgcn_mfma_f32_16x16x32_bf16(av, b1, acc1, 0, 0, 0);
        acc2 = __builtin_amdgcn_mfma_f32_16x16x32_bf16(av, b2, acc2, 0, 0, 0);
        acc3 = __builtin_amdgcn_mfma_f32_16x16x32_bf16(av, b3, acc3, 0, 0, 0);
    }
    int nbase = n0 + kg*4;
    u16* zp = z + ((size_t)nbase*NH + h)*HD + c0 + r16;
    #pragma unroll
    for(int reg = 0; reg < 4; ++reg){
        u16* q = zp + (size_t)reg*NH*HD;
        q[0]  = f2bf(acc0[reg]);
        q[16] = f2bf(acc1[reg]);
        q[32] = f2bf(acc2[reg]);
        q[48] = f2bf(acc3[reg]);
    }
}

// ---- per-node attention dot products, head-phased; z [n][h][c] -------------
__global__ void k_dots(const u16* __restrict__ z, const float* __restrict__ attj,
                       float* __restrict__ es, float* __restrict__ ed){
    int tx = threadIdx.x, lane = tx & 63, w = tx >> 6;
    int n = blockIdx.x*4 + w;
    int h = blockIdx.y;
    int ch = lane*2;
    u32 zz = *(const u32*)(z + ((size_t)n*NH + h)*HD + ch);
    float z0 = bflo(zz), z1 = bfhi(zz);
    const float* a = attj + h*2*HD;
    float ps = z0*a[ch]    + z1*a[ch+1];
    float pd = z0*a[HD+ch] + z1*a[HD+ch+1];
    #pragma unroll
    for(int d = 32; d > 0; d >>= 1){ ps += __shfl_xor(ps, d); pd += __shfl_xor(pd, d); }
    if(lane == 0){ es[(size_t)h*NN + n] = ps; ed[(size_t)h*NN + n] = pd; }
}

// ---- fused edge-logit + segment softmax + aggregation + relu ---------------
// ONE WAVE PER NODE, all 4 heads: lane = (h = lane>>4, cidx = lane&15).
// Each lane owns 8 channels of head h -> NO accumulator-combine epilogue;
// ssum reduce = 4 shfl_xor within 16-lane groups. One prologue per node
// (not per node-head). Per edge the wave's 64 lanes read one contiguous
// 1KB z row ([n][h][c] layout). Inner loop: 4 edges/iter = 4 independent
// dwordx4 loads per lane (broadcast (a,s) via shfl, register-only dep).
__global__ void k_aggregate(const int* __restrict__ rowptr, const int* __restrict__ srcs,
                            const float* __restrict__ es, const float* __restrict__ ed,
                            const u16* __restrict__ z, u16* __restrict__ r){
    int tx = threadIdx.x, lane = tx & 63, w = tx >> 6;
    int n = blockIdx.x*4 + w;
    int h = lane >> 4;           // 0..3
    int cidx = lane & 15;        // channel group: cidx*8 .. +7
    int p0 = rowptr[n], p1 = rowptr[n+1];
    const float* esh = es + (size_t)h*NN;
    float edn = ed[(size_t)h*NN + n];
    int bidx = lane & 48;        // h*16: shfl base for this head's edge slots
    float ssum = 0.f;
    f32x2 acc[4];
    #pragma unroll
    for(int k = 0; k < 4; ++k) acc[k] = (f32x2){0.f, 0.f};

    for(int base = p0; base < p1; base += 16){
        int p = base + cidx;
        int sn = 0; float ex = 0.f;
        if(p < p1){
            sn = srcs[p];
            float e = esh[sn] + edn;
            e = e >= 0.f ? e : 0.01f*e;          // leaky_relu slope 0.01
            ex = __expf(e);
        }
        ssum += ex;
        int cnt = min(16, p1 - base);
        for(int jj = 0; jj < cnt; jj += 4){
            float a0 = __shfl(ex, bidx + jj);
            int   s0 = __shfl(sn, bidx + jj);
            float a1 = __shfl(ex, bidx + jj + 1);
            int   s1 = __shfl(sn, bidx + jj + 1);
            float a2 = __shfl(ex, bidx + jj + 2);
            int   s2 = __shfl(sn, bidx + jj + 2);
            float a3 = __shfl(ex, bidx + jj + 3);
            int   s3 = __shfl(sn, bidx + jj + 3);
            uint4 v0 = *(const uint4*)(z + ((size_t)s0*NH + h)*HD + cidx*8);
            uint4 v1 = *(const uint4*)(z + ((size_t)s1*NH + h)*HD + cidx*8);
            uint4 v2 = *(const uint4*)(z + ((size_t)s2*NH + h)*HD + cidx*8);
            uint4 v3 = *(const uint4*)(z + ((size_t)s3*NH + h)*HD + cidx*8);
            f32x2 t;
            t.x = bflo(v0.x); t.y = bfhi(v0.x); acc[0] += a0*t;
            t.x = bflo(v0.y); t.y = bfhi(v0.y); acc[1] += a0*t;
            t.x = bflo(v0.z); t.y = bfhi(v0.z); acc[2] += a0*t;
            t.x = bflo(v0.w); t.y = bfhi(v0.w); acc[3] += a0*t;
            t.x = bflo(v1.x); t.y = bfhi(v1.x); acc[0] += a1*t;
            t.x = bflo(v1.y); t.y = bfhi(v1.y); acc[1] += a1*t;
            t.x = bflo(v1.z); t.y = bfhi(v1.z); acc[2] += a1*t;
            t.x = bflo(v1.w); t.y = bfhi(v1.w); acc[3] += a1*t;
            t.x = bflo(v2.x); t.y = bfhi(v2.x); acc[0] += a2*t;
            t.x = bflo(v2.y); t.y = bfhi(v2.y); acc[1] += a2*t;
            t.x = bflo(v2.z); t.y = bfhi(v2.z); acc[2] += a2*t;
            t.x = bflo(v2.w); t.y = bfhi(v2.w); acc[3] += a2*t;
            t.x = bflo(v3.x); t.y = bfhi(v3.x); acc[0] += a3*t;
            t.x = bflo(v3.y); t.y = bfhi(v3.y); acc[1] += a3*t;
            t.x = bflo(v3.z); t.y = bfhi(v3.z); acc[2] += a3*t;
            t.x = bflo(v3.w); t.y = bfhi(v3.w); acc[3] += a3*t;
        }
    }
    // ssum: reduce within each head's 16-lane group
    ssum += __shfl_xor(ssum, 1);
    ssum += __shfl_xor(ssum, 2);
    ssum += __shfl_xor(ssum, 4);
    ssum += __shfl_xor(ssum, 8);
    float inv = (ssum > 0.f) ? 1.f/ssum : 0.f;
    uint4 o;
    o.x = pack2(fmaxf(acc[0].x*inv, 0.f), fmaxf(acc[0].y*inv, 0.f));
    o.y = pack2(fmaxf(acc[1].x*inv, 0.f), fmaxf(acc[1].y*inv, 0.f));
    o.z = pack2(fmaxf(acc[2].x*inv, 0.f), fmaxf(acc[2].y*inv, 0.f));
    o.w = pack2(fmaxf(acc[3].x*inv, 0.f), fmaxf(acc[3].y*inv, 0.f));
    *(uint4*)(r + ((size_t)n*NH + h)*HD + cidx*8) = o;
}

// ---- BatchNorm stats (sum, sumsq per channel) ------------------------------
__global__ void k_bnreduce(const u16* __restrict__ r, float* __restrict__ bnsum,
                           float* __restrict__ bnsqs){
    int c = blockIdx.x*256 + threadIdx.x;   // 0..511
    int nbeg = blockIdx.y * 160;            // 125 chunks * 160 = 20000
    float s = 0.f, s2 = 0.f;
    for(int i = 0; i < 160; ++i){
        float v = bf2f(r[(size_t)(nbeg+i)*512 + c]);
        s += v; s2 += v*v;
    }
    atomicAdd(&bnsum[c], s);
    atomicAdd(&bnsqs[c], s2);
}

// ---- BN finalize (in-block) + BN apply + head softmax mix ------------------
// out_b omitted: softmax(v + const) == softmax(v)
__global__ void k_headmix(const u16* __restrict__ r, const float* __restrict__ bnsum,
                          const float* __restrict__ bnsqs, const float* __restrict__ gamma,
                          const float* __restrict__ beta, const float* __restrict__ ow,
                          u16* __restrict__ x){
    __shared__ float sinv[512], sshift[512];
    int tx = threadIdx.x;
    #pragma unroll
    for(int c = tx; c < 512; c += 256){
        float mean = bnsum[c] * (1.f/NN);
        float var  = bnsqs[c] * (1.f/NN) - mean*mean;
        float iv = gamma[c] * rsqrtf(var + BN_EPS);
        sinv[c] = iv;
        sshift[c] = beta[c] - mean*iv;
    }
    __syncthreads();
    int lane = tx & 63, w = tx >> 6;
    int n = blockIdx.x*4 + w;
    int ch = lane*2;
    float rn[NH][2];
    float sc[NH];
    #pragma unroll
    for(int h = 0; h < NH; ++h){
        int c = h*HD + ch;
        u32 zz = *(const u32*)(r + (size_t)n*512 + c);
        float v0 = bflo(zz)*sinv[c]   + sshift[c];
        float v1 = bfhi(zz)*sinv[c+1] + sshift[c+1];
        rn[h][0] = v0; rn[h][1] = v1;
        float p = v0*ow[ch] + v1*ow[ch+1];
        #pragma unroll
        for(int d = 32; d > 0; d >>= 1) p += __shfl_xor(p, d);
        sc[h] = p;
    }
    float m = fmaxf(fmaxf(sc[0], sc[1]), fmaxf(sc[2], sc[3]));
    float e0 = __expf(sc[0]-m), e1 = __expf(sc[1]-m), e2 = __expf(sc[2]-m), e3 = __expf(sc[3]-m);
    float is = 1.f/(e0+e1+e2+e3);
    float x0 = (e0*rn[0][0] + e1*rn[1][0] + e2*rn[2][0] + e3*rn[3][0])*is;
    float x1 = (e0*rn[0][1] + e1*rn[1][1] + e2*rn[2][1] + e3*rn[3][1])*is;
    *(u32*)(x + (size_t)n*HD + ch) = pack2(x0, x1);
}

// ---- per-graph mean (graph_ids sorted -> contiguous ranges, no atomics) ----
__global__ void k_gmean(const int* __restrict__ gid, const u16* __restrict__ x,
                        float* __restrict__ out){
    int g = blockIdx.x;
    int tx = threadIdx.x, lane = tx & 63, w = tx >> 6;
    int lo = 0, hi = NN;
    while(lo < hi){ int mid = (lo + hi) >> 1; if(gid[mid] < g) lo = mid + 1; else hi = mid; }
    int start = lo;
    hi = NN;
    while(lo < hi){ int mid = (lo + hi) >> 1; if(gid[mid] < g + 1) lo = mid + 1; else hi = mid; }
    int end = lo;
    float a0 = 0.f, a1 = 0.f;
    for(int n = start + w; n < end; n += 4){
        u32 zz = *(const u32*)(x + (size_t)n*HD + lane*2);
        a0 += bflo(zz);
        a1 += bfhi(zz);
    }
    __shared__ float sm[4][HD];
    sm[w][lane*2]     = a0;
    sm[w][lane*2 + 1] = a1;
    __syncthreads();
    if(tx < HD){
        float s = sm[0][tx] + sm[1][tx] + sm[2][tx] + sm[3][tx];
        float cnt = (float)(end - start);
        out[g*HD + tx] = s / fmaxf(cnt, 1.f);
    }
}

extern "C" void kernel_launch(void* const* d_in, const int* in_sizes, int n_in,
                              void* d_out, int out_size, void* d_ws, size_t ws_size,
                              hipStream_t stream){
    const float* h     = (const float*)d_in[0];
    const int*   src   = (const int*)  d_in[1];
    const int*   dst   = (const int*)  d_in[2];
    const int*   gid   = (const int*)  d_in[3];
    const float* W0    = (const float*)d_in[4];
    const float* Wr    = (const float*)d_in[5];
    const float* att   = (const float*)d_in[6];
    const float* gamma = (const float*)d_in[7];
    const float* beta  = (const float*)d_in[8];
    const float* ow    = (const float*)d_in[9];

    char* p = (char*)d_ws;
    auto alloc = [&](size_t bytes) -> void* {
        void* q = (void*)p;
        p += (bytes + 255) & ~(size_t)255;
        return q;
    };
    u16*   z      = (u16*)  alloc((size_t)NN*NH*HD*2);   // 20.5 MB, [n][h][c]
    u16*   r      = (u16*)  alloc((size_t)NN*NH*HD*2);   // 20.5 MB, [n][h][c]
    u16*   x      = (u16*)  alloc((size_t)NN*HD*2);      // 5.1 MB
    u16*   hb     = (u16*)  alloc((size_t)NN*KP0*2);     // 3.8 MB
    u16*   wt0    = (u16*)  alloc((size_t)NH*HD*KP0*2);
    u16*   wt1    = (u16*)  alloc((size_t)NH*HD*HD*2);
    float* es     = (float*)alloc((size_t)NN*NH*4);      // [h][n]
    float* ed     = (float*)alloc((size_t)NN*NH*4);      // [h][n]
    int*   counts = (int*)  alloc((size_t)NN*4);
    int*   rowptr = (int*)  alloc((size_t)(NN+1)*4);
    int*   cursor = (int*)  alloc((size_t)NN*4);
    int*   srcs   = (int*)  alloc((size_t)NE*4);
    int*   tsum   = (int*)  alloc((size_t)SCAN_B*4);
    float* bnstat = (float*)alloc(2048*4);               // [layer][sum512|sqs512]

    // fused prep: conversions + zero counts + zero bnstat (both layers)
    k_prep<<<(PREP_TOT+255)/256, 256, 0, stream>>>(h, W0, Wr, hb, wt0, wt1,
                                                   counts, bnstat);

    // CSR build (graph is identical both layers)
    k_hist   <<<(NE+255)/256, 256, 0, stream>>>(dst, counts);
    k_scan1  <<<SCAN_B, 1024, 0, stream>>>(counts, rowptr, tsum);
    k_scan3  <<<SCAN_B, 1024, 0, stream>>>(rowptr, tsum, cursor);
    k_scatter<<<(NE+255)/256, 256, 0, stream>>>(src, dst, cursor, srcs);

    for(int j = 0; j < 2; ++j){
        const float* attj = att + j*NH*2*HD;
        if(j == 0) k_gemm_mfma<KP0><<<dim3(NN/32, NH), 256, 0, stream>>>(hb, wt0, z);
        else       k_gemm_mfma<HD> <<<dim3(NN/32, NH), 256, 0, stream>>>(x,  wt1, z);

        k_dots     <<<dim3(NN/4, NH), 256, 0, stream>>>(z, attj, es, ed);
        k_aggregate<<<NN/4, 256, 0, stream>>>(rowptr, srcs, es, ed, z, r);

        k_bnreduce <<<dim3(2,125), 256, 0, stream>>>(r, bnstat + j*1024, bnstat + j*1024 + 512);
        k_headmix  <<<NN/4, 256, 0, stream>>>(r, bnstat + j*1024, bnstat + j*1024 + 512,
                                              gamma + j*512, beta + j*512, ow + j*HD, x);
    }

    k_gmean<<<NG, 256, 0, stream>>>(gid, x, (float*)d_out);
}

// Round 13
// 259.659 us; speedup vs baseline: 1.0270x; 1.0270x over previous
//
#include <hip/hip_runtime.h>
#include <hip/hip_bf16.h>

typedef unsigned short u16;
typedef unsigned int u32;
typedef __attribute__((ext_vector_type(8))) short bf16x8;
typedef __attribute__((ext_vector_type(4))) float f32x4;
typedef __attribute__((ext_vector_type(2))) float f32x2;

#define NN 20000      // nodes
#define NE 320000     // edges
#define NG 128        // graphs
#define HD 128        // hidden
#define NH 4          // heads
#define KIN 74        // input features
#define KP0 96        // KIN padded to multiple of 32
#define BN_EPS 1e-5f
#define SCAN_B 20     // ceil(NN/1024)

__device__ __forceinline__ float bf2f(u16 v){ return __uint_as_float(((u32)v)<<16); }
__device__ __forceinline__ float bflo(u32 v){ return __uint_as_float(v<<16); }
__device__ __forceinline__ float bfhi(u32 v){ return __uint_as_float(v & 0xffff0000u); }
__device__ __forceinline__ u16 f2bf(float f){
    u32 u = __float_as_uint(f);
    return (u16)((u + 0x7fffu + ((u>>16)&1u)) >> 16);   // RNE
}
__device__ __forceinline__ u32 pack2(float a, float b){
    return (u32)f2bf(a) | ((u32)f2bf(b) << 16);
}

// ---- fused prep: bf16 conversions + zero counts + zero bnstat ---------------
#define PREP_S0 (NN*KP0)
#define PREP_S1 (NH*HD*KP0)
#define PREP_S2 (NH*HD*HD)
#define PREP_TOT (PREP_S0 + PREP_S1 + PREP_S2 + NN + 2048)
__global__ void k_prep(const float* __restrict__ h, const float* __restrict__ W0,
                       const float* __restrict__ Wr, u16* __restrict__ hb,
                       u16* __restrict__ wt0, u16* __restrict__ wt1,
                       int* __restrict__ counts, float* __restrict__ bnstat){
    int i = blockIdx.x*256 + threadIdx.x;
    if(i < PREP_S0){
        int n = i/KP0, k = i - n*KP0;
        hb[i] = (k < KIN) ? f2bf(h[n*KIN + k]) : (u16)0;
        return;
    }
    i -= PREP_S0;
    if(i < PREP_S1){                       // W0[h][k][c] -> wt0[h][c][KP0]
        int k = i % KP0; int c = (i/KP0) % HD; int hh = i/(KP0*HD);
        wt0[i] = (k < KIN) ? f2bf(W0[(hh*KIN + k)*HD + c]) : (u16)0;
        return;
    }
    i -= PREP_S1;
    if(i < PREP_S2){                       // Wr[h][k][c] -> wt1[h][c][HD]
        int k = i % HD; int c = (i/HD) % HD; int hh = i/(HD*HD);
        wt1[i] = f2bf(Wr[(hh*HD + k)*HD + c]);
        return;
    }
    i -= PREP_S2;
    if(i < NN){ counts[i] = 0; return; }
    i -= NN;
    if(i < 2048) bnstat[i] = 0.f;
}

// ---- CSR build -------------------------------------------------------------
__global__ void k_hist(const int* __restrict__ dst, int* __restrict__ counts){
    int e = blockIdx.x*256 + threadIdx.x;
    if(e < NE) atomicAdd(&counts[dst[e]], 1);
}

__global__ void k_scan1(const int* __restrict__ counts, int* __restrict__ rowptr,
                        int* __restrict__ tsum){
    __shared__ int wsum[16];
    int tx = threadIdx.x, lane = tx & 63, wid = tx >> 6;
    int i = blockIdx.x*1024 + tx;
    int v = (i < NN) ? counts[i] : 0;
    int s = v;
    #pragma unroll
    for(int d = 1; d < 64; d <<= 1){ int o = __shfl_up(s, d); if(lane >= d) s += o; }
    if(lane == 63) wsum[wid] = s;
    __syncthreads();
    int woff = 0, total = 0;
    #pragma unroll
    for(int w_ = 0; w_ < 16; ++w_){ int sw = wsum[w_]; total += sw; if(w_ < wid) woff += sw; }
    if(i < NN) rowptr[i] = woff + s - v;     // tile-local exclusive
    if(tx == 0) tsum[blockIdx.x] = total;
}

__global__ void k_scan3(int* __restrict__ rowptr, const int* __restrict__ tsum,
                        int* __restrict__ cursor){
    __shared__ int s_off;
    int tx = threadIdx.x;
    if(tx < 64){
        int v = (tx < SCAN_B && tx < (int)blockIdx.x) ? tsum[tx] : 0;
        #pragma unroll
        for(int d = 32; d > 0; d >>= 1) v += __shfl_xor(v, d);
        if(tx == 0) s_off = v;
    }
    __syncthreads();
    int i = blockIdx.x*1024 + tx;
    if(i < NN){
        int val = rowptr[i] + s_off;
        rowptr[i] = val;
        cursor[i] = val;
    }
    if(blockIdx.x == 0 && tx == 0) rowptr[NN] = NE;
}

__global__ void k_scatter(const int* __restrict__ src, const int* __restrict__ dst,
                          int* __restrict__ cursor, int* __restrict__ srcs){
    int e = blockIdx.x*256 + threadIdx.x;
    if(e >= NE) return;
    int d = dst[e];
    int p = atomicAdd(&cursor[d], 1);
    srcs[p] = src[e];
}

// ---- z = x @ W per head via MFMA; z layout [h][n][c] (r11 verbatim) --------
template<int KP>
__global__ void k_gemm_mfma(const u16* __restrict__ xb, const u16* __restrict__ wt,
                            u16* __restrict__ z){
    int h = blockIdx.y;
    int tx = threadIdx.x, lane = tx & 63, w = tx >> 6;
    int n0 = blockIdx.x*32 + (w >> 1)*16;
    int c0 = (w & 1)*64;
    int r16 = lane & 15, kg = lane >> 4;
    const u16* ap = xb + (size_t)(n0 + r16)*KP + kg*8;
    const u16* bp = wt + ((size_t)h*HD + c0 + r16)*KP + kg*8;
    f32x4 acc0 = {0.f,0.f,0.f,0.f}, acc1 = {0.f,0.f,0.f,0.f};
    f32x4 acc2 = {0.f,0.f,0.f,0.f}, acc3 = {0.f,0.f,0.f,0.f};
    #pragma unroll
    for(int k0 = 0; k0 < KP; k0 += 32){
        bf16x8 av = *(const bf16x8*)(ap + k0);
        bf16x8 b0 = *(const bf16x8*)(bp + k0);
        bf16x8 b1 = *(const bf16x8*)(bp + 16*KP + k0);
        bf16x8 b2 = *(const bf16x8*)(bp + 32*KP + k0);
        bf16x8 b3 = *(const bf16x8*)(bp + 48*KP + k0);
        acc0 = __builtin_amdgcn_mfma_f32_16x16x32_bf16(av, b0, acc0, 0, 0, 0);
        acc1 = __builtin_amdgcn_mfma_f32_16x16x32_bf16(av, b1, acc1, 0, 0, 0);
        acc2 = __builtin_amdgcn_mfma_f32_16x16x32_bf16(av, b2, acc2, 0, 0, 0);
        acc3 = __builtin_amdgcn_mfma_f32_16x16x32_bf16(av, b3, acc3, 0, 0, 0);
    }
    int nbase = n0 + kg*4;
    u16* zp = z + ((size_t)h*NN + nbase)*HD + c0 + r16;
    #pragma unroll
    for(int reg = 0; reg < 4; ++reg){
        u16* q = zp + (size_t)reg*HD;
        q[0]  = f2bf(acc0[reg]);
        q[16] = f2bf(acc1[reg]);
        q[32] = f2bf(acc2[reg]);
        q[48] = f2bf(acc3[reg]);
    }
}

// ---- per-node attention dot products, head-phased (r11 verbatim) -----------
__global__ void k_dots(const u16* __restrict__ z, const float* __restrict__ attj,
                       float* __restrict__ es, float* __restrict__ ed){
    int tx = threadIdx.x, lane = tx & 63, w = tx >> 6;
    int n = blockIdx.x*4 + w;
    int h = blockIdx.y;
    int ch = lane*2;
    u32 zz = *(const u32*)(z + ((size_t)h*NN + n)*HD + ch);
    float z0 = bflo(zz), z1 = bfhi(zz);
    const float* a = attj + h*2*HD;
    float ps = z0*a[ch]    + z1*a[ch+1];
    float pd = z0*a[HD+ch] + z1*a[HD+ch+1];
    #pragma unroll
    for(int d = 32; d > 0; d >>= 1){ ps += __shfl_xor(ps, d); pd += __shfl_xor(pd, d); }
    if(lane == 0){ es[(size_t)h*NN + n] = ps; ed[(size_t)h*NN + n] = pd; }
}

// ---- fused edge-logit + segment softmax + aggregation + relu ---------------
// r11 structure; inner loop widened to 16 edges / 4 independent dwordx4 loads
// in flight per lane. Per-lane edge accumulation ORDER is identical to r11
// (eslot, eslot+4, eslot+8, eslot+12, ...) -> bit-identical output.
__global__ void k_aggregate(const int* __restrict__ rowptr, const int* __restrict__ srcs,
                            const float* __restrict__ es, const float* __restrict__ ed,
                            const u16* __restrict__ z, u16* __restrict__ r){
    int tx = threadIdx.x, lane = tx & 63, w = tx >> 6;
    int n = blockIdx.x*4 + w;
    int h = blockIdx.y;
    int p0 = rowptr[n], p1 = rowptr[n+1];
    int eslot = lane >> 4;       // 0..3
    int cidx  = lane & 15;       // 8 channels: cidx*8 .. +7
    const float* esh = es + (size_t)h*NN;
    const u16*   zh  = z  + (size_t)h*NN*HD;
    float edn = ed[(size_t)h*NN + n];
    float ssum = 0.f;
    f32x2 acc[4];
    #pragma unroll
    for(int k = 0; k < 4; ++k) acc[k] = (f32x2){0.f, 0.f};

    for(int base = p0; base < p1; base += 64){
        int p = base + lane;
        int sn = 0; float ex = 0.f;
        if(p < p1){
            sn = srcs[p];
            float e = esh[sn] + edn;
            e = e >= 0.f ? e : 0.01f*e;          // leaky_relu slope 0.01
            ex = __expf(e);
        }
        ssum += ex;
        int cnt = min(64, p1 - base);
        int niter = (cnt + 15) >> 4;             // 16 edges per iteration
        for(int i = 0; i < niter; ++i){
            int e0 = i*16 + eslot;               // <= 51
            float a0 = __shfl(ex, e0);
            int   s0 = __shfl(sn, e0);
            float a1 = __shfl(ex, e0 + 4);
            int   s1 = __shfl(sn, e0 + 4);
            float a2 = __shfl(ex, e0 + 8);
            int   s2 = __shfl(sn, e0 + 8);
            float a3 = __shfl(ex, e0 + 12);      // <= 63 (ex==0 past cnt)
            int   s3 = __shfl(sn, e0 + 12);
            uint4 v0 = *(const uint4*)(zh + (size_t)s0*HD + cidx*8);
            uint4 v1 = *(const uint4*)(zh + (size_t)s1*HD + cidx*8);
            uint4 v2 = *(const uint4*)(zh + (size_t)s2*HD + cidx*8);
            uint4 v3 = *(const uint4*)(zh + (size_t)s3*HD + cidx*8);
            f32x2 t;
            t.x = bflo(v0.x); t.y = bfhi(v0.x); acc[0] += a0*t;
            t.x = bflo(v0.y); t.y = bfhi(v0.y); acc[1] += a0*t;
            t.x = bflo(v0.z); t.y = bfhi(v0.z); acc[2] += a0*t;
            t.x = bflo(v0.w); t.y = bfhi(v0.w); acc[3] += a0*t;
            t.x = bflo(v1.x); t.y = bfhi(v1.x); acc[0] += a1*t;
            t.x = bflo(v1.y); t.y = bfhi(v1.y); acc[1] += a1*t;
            t.x = bflo(v1.z); t.y = bfhi(v1.z); acc[2] += a1*t;
            t.x = bflo(v1.w); t.y = bfhi(v1.w); acc[3] += a1*t;
            t.x = bflo(v2.x); t.y = bfhi(v2.x); acc[0] += a2*t;
            t.x = bflo(v2.y); t.y = bfhi(v2.y); acc[1] += a2*t;
            t.x = bflo(v2.z); t.y = bfhi(v2.z); acc[2] += a2*t;
            t.x = bflo(v2.w); t.y = bfhi(v2.w); acc[3] += a2*t;
            t.x = bflo(v3.x); t.y = bfhi(v3.x); acc[0] += a3*t;
            t.x = bflo(v3.y); t.y = bfhi(v3.y); acc[1] += a3*t;
            t.x = bflo(v3.z); t.y = bfhi(v3.z); acc[2] += a3*t;
            t.x = bflo(v3.w); t.y = bfhi(v3.w); acc[3] += a3*t;
        }
    }
    float c01[8];
    #pragma unroll
    for(int k = 0; k < 4; ++k){
        float a0 = acc[k].x, a1 = acc[k].y;
        a0 += __shfl_xor(a0, 16); a0 += __shfl_xor(a0, 32);
        a1 += __shfl_xor(a1, 16); a1 += __shfl_xor(a1, 32);
        c01[k*2] = a0; c01[k*2+1] = a1;
    }
    #pragma unroll
    for(int d = 32; d > 0; d >>= 1) ssum += __shfl_xor(ssum, d);
    float inv = (ssum > 0.f) ? 1.f/ssum : 0.f;
    if(eslot == 0){
        uint4 o;
        o.x = pack2(fmaxf(c01[0]*inv, 0.f), fmaxf(c01[1]*inv, 0.f));
        o.y = pack2(fmaxf(c01[2]*inv, 0.f), fmaxf(c01[3]*inv, 0.f));
        o.z = pack2(fmaxf(c01[4]*inv, 0.f), fmaxf(c01[5]*inv, 0.f));
        o.w = pack2(fmaxf(c01[6]*inv, 0.f), fmaxf(c01[7]*inv, 0.f));
        *(uint4*)(r + ((size_t)n*NH + h)*HD + cidx*8) = o;
    }
}

// ---- BatchNorm stats (sum, sumsq per channel) (r11 verbatim) ---------------
__global__ void k_bnreduce(const u16* __restrict__ r, float* __restrict__ bnsum,
                           float* __restrict__ bnsqs){
    int c = blockIdx.x*256 + threadIdx.x;   // 0..511
    int nbeg = blockIdx.y * 160;            // 125 chunks * 160 = 20000
    float s = 0.f, s2 = 0.f;
    for(int i = 0; i < 160; ++i){
        float v = bf2f(r[(size_t)(nbeg+i)*512 + c]);
        s += v; s2 += v*v;
    }
    atomicAdd(&bnsum[c], s);
    atomicAdd(&bnsqs[c], s2);
}

// ---- BN finalize (in-block) + BN apply + head softmax mix (r11 verbatim) ---
__global__ void k_headmix(const u16* __restrict__ r, const float* __restrict__ bnsum,
                          const float* __restrict__ bnsqs, const float* __restrict__ gamma,
                          const float* __restrict__ beta, const float* __restrict__ ow,
                          u16* __restrict__ x){
    __shared__ float sinv[512], sshift[512];
    int tx = threadIdx.x;
    #pragma unroll
    for(int c = tx; c < 512; c += 256){
        float mean = bnsum[c] * (1.f/NN);
        float var  = bnsqs[c] * (1.f/NN) - mean*mean;
        float iv = gamma[c] * rsqrtf(var + BN_EPS);
        sinv[c] = iv;
        sshift[c] = beta[c] - mean*iv;
    }
    __syncthreads();
    int lane = tx & 63, w = tx >> 6;
    int n = blockIdx.x*4 + w;
    int ch = lane*2;
    float rn[NH][2];
    float sc[NH];
    #pragma unroll
    for(int h = 0; h < NH; ++h){
        int c = h*HD + ch;
        u32 zz = *(const u32*)(r + (size_t)n*512 + c);
        float v0 = bflo(zz)*sinv[c]   + sshift[c];
        float v1 = bfhi(zz)*sinv[c+1] + sshift[c+1];
        rn[h][0] = v0; rn[h][1] = v1;
        float p = v0*ow[ch] + v1*ow[ch+1];
        #pragma unroll
        for(int d = 32; d > 0; d >>= 1) p += __shfl_xor(p, d);
        sc[h] = p;
    }
    float m = fmaxf(fmaxf(sc[0], sc[1]), fmaxf(sc[2], sc[3]));
    float e0 = __expf(sc[0]-m), e1 = __expf(sc[1]-m), e2 = __expf(sc[2]-m), e3 = __expf(sc[3]-m);
    float is = 1.f/(e0+e1+e2+e3);
    float x0 = (e0*rn[0][0] + e1*rn[1][0] + e2*rn[2][0] + e3*rn[3][0])*is;
    float x1 = (e0*rn[0][1] + e1*rn[1][1] + e2*rn[2][1] + e3*rn[3][1])*is;
    *(u32*)(x + (size_t)n*HD + ch) = pack2(x0, x1);
}

// ---- per-graph mean (r11 verbatim) ------------------------------------------
__global__ void k_gmean(const int* __restrict__ gid, const u16* __restrict__ x,
                        float* __restrict__ out){
    int g = blockIdx.x;
    int tx = threadIdx.x, lane = tx & 63, w = tx >> 6;
    int lo = 0, hi = NN;
    while(lo < hi){ int mid = (lo + hi) >> 1; if(gid[mid] < g) lo = mid + 1; else hi = mid; }
    int start = lo;
    hi = NN;
    while(lo < hi){ int mid = (lo + hi) >> 1; if(gid[mid] < g + 1) lo = mid + 1; else hi = mid; }
    int end = lo;
    float a0 = 0.f, a1 = 0.f;
    for(int n = start + w; n < end; n += 4){
        u32 zz = *(const u32*)(x + (size_t)n*HD + lane*2);
        a0 += bflo(zz);
        a1 += bfhi(zz);
    }
    __shared__ float sm[4][HD];
    sm[w][lane*2]     = a0;
    sm[w][lane*2 + 1] = a1;
    __syncthreads();
    if(tx < HD){
        float s = sm[0][tx] + sm[1][tx] + sm[2][tx] + sm[3][tx];
        float cnt = (float)(end - start);
        out[g*HD + tx] = s / fmaxf(cnt, 1.f);
    }
}

extern "C" void kernel_launch(void* const* d_in, const int* in_sizes, int n_in,
                              void* d_out, int out_size, void* d_ws, size_t ws_size,
                              hipStream_t stream){
    const float* h     = (const float*)d_in[0];
    const int*   src   = (const int*)  d_in[1];
    const int*   dst   = (const int*)  d_in[2];
    const int*   gid   = (const int*)  d_in[3];
    const float* W0    = (const float*)d_in[4];
    const float* Wr    = (const float*)d_in[5];
    const float* att   = (const float*)d_in[6];
    const float* gamma = (const float*)d_in[7];
    const float* beta  = (const float*)d_in[8];
    const float* ow    = (const float*)d_in[9];

    char* p = (char*)d_ws;
    auto alloc = [&](size_t bytes) -> void* {
        void* q = (void*)p;
        p += (bytes + 255) & ~(size_t)255;
        return q;
    };
    u16*   z      = (u16*)  alloc((size_t)NN*NH*HD*2);   // 20.5 MB, [h][n][c]
    u16*   r      = (u16*)  alloc((size_t)NN*NH*HD*2);   // 20.5 MB, [n][h][c]
    u16*   x      = (u16*)  alloc((size_t)NN*HD*2);      // 5.1 MB
    u16*   hb     = (u16*)  alloc((size_t)NN*KP0*2);     // 3.8 MB
    u16*   wt0    = (u16*)  alloc((size_t)NH*HD*KP0*2);
    u16*   wt1    = (u16*)  alloc((size_t)NH*HD*HD*2);
    float* es     = (float*)alloc((size_t)NN*NH*4);      // [h][n]
    float* ed     = (float*)alloc((size_t)NN*NH*4);      // [h][n]
    int*   counts = (int*)  alloc((size_t)NN*4);
    int*   rowptr = (int*)  alloc((size_t)(NN+1)*4);
    int*   cursor = (int*)  alloc((size_t)NN*4);
    int*   srcs   = (int*)  alloc((size_t)NE*4);
    int*   tsum   = (int*)  alloc((size_t)SCAN_B*4);
    float* bnstat = (float*)alloc(2048*4);               // [layer][sum512|sqs512]

    // fused prep: conversions + zero counts + zero bnstat (both layers)
    k_prep<<<(PREP_TOT+255)/256, 256, 0, stream>>>(h, W0, Wr, hb, wt0, wt1,
                                                   counts, bnstat);

    // CSR build (graph is identical both layers)
    k_hist   <<<(NE+255)/256, 256, 0, stream>>>(dst, counts);
    k_scan1  <<<SCAN_B, 1024, 0, stream>>>(counts, rowptr, tsum);
    k_scan3  <<<SCAN_B, 1024, 0, stream>>>(rowptr, tsum, cursor);
    k_scatter<<<(NE+255)/256, 256, 0, stream>>>(src, dst, cursor, srcs);

    for(int j = 0; j < 2; ++j){
        const float* attj = att + j*NH*2*HD;
        if(j == 0) k_gemm_mfma<KP0><<<dim3(NN/32, NH), 256, 0, stream>>>(hb, wt0, z);
        else       k_gemm_mfma<HD> <<<dim3(NN/32, NH), 256, 0, stream>>>(x,  wt1, z);

        k_dots     <<<dim3(NN/4, NH), 256, 0, stream>>>(z, attj, es, ed);
        k_aggregate<<<dim3(NN/4, NH), 256, 0, stream>>>(rowptr, srcs, es, ed, z, r);

        k_bnreduce <<<dim3(2,125), 256, 0, stream>>>(r, bnstat + j*1024, bnstat + j*1024 + 512);
        k_headmix  <<<NN/4, 256, 0, stream>>>(r, bnstat + j*1024, bnstat + j*1024 + 512,
                                              gamma + j*512, beta + j*512, ow + j*HD, x);
    }

    k_gmean<<<NG, 256, 0, stream>>>(gid, x, (float*)d_out);
}

// Round 14
// 239.482 us; speedup vs baseline: 1.1135x; 1.0843x over previous
//
#include <hip/hip_runtime.h>
#include <hip/hip_bf16.h>

typedef unsigned short u16;
typedef unsigned int u32;
typedef __attribute__((ext_vector_type(8))) short bf16x8;
typedef __attribute__((ext_vector_type(4))) float f32x4;
typedef __attribute__((ext_vector_type(2))) float f32x2;

#define NN 20000      // nodes
#define NE 320000     // edges
#define NG 128        // graphs
#define HD 128        // hidden
#define NH 4          // heads
#define KIN 74        // input features
#define KP0 96        // KIN padded to multiple of 32
#define BN_EPS 1e-5f
#define SCAN_B 20     // ceil(NN/1024)

__device__ __forceinline__ float bf2f(u16 v){ return __uint_as_float(((u32)v)<<16); }
__device__ __forceinline__ float bflo(u32 v){ return __uint_as_float(v<<16); }
__device__ __forceinline__ float bfhi(u32 v){ return __uint_as_float(v & 0xffff0000u); }
__device__ __forceinline__ u16 f2bf(float f){
    u32 u = __float_as_uint(f);
    return (u16)((u + 0x7fffu + ((u>>16)&1u)) >> 16);   // RNE
}
__device__ __forceinline__ u32 pack2(float a, float b){
    return (u32)f2bf(a) | ((u32)f2bf(b) << 16);
}

// ---- fused prep: bf16 conversions + zero counts + zero bnstat ---------------
#define PREP_S0 (NN*KP0)
#define PREP_S1 (NH*HD*KP0)
#define PREP_S2 (NH*HD*HD)
#define PREP_TOT (PREP_S0 + PREP_S1 + PREP_S2 + NN + 2048)
__global__ void k_prep(const float* __restrict__ h, const float* __restrict__ W0,
                       const float* __restrict__ Wr, u16* __restrict__ hb,
                       u16* __restrict__ wt0, u16* __restrict__ wt1,
                       int* __restrict__ counts, float* __restrict__ bnstat){
    int i = blockIdx.x*256 + threadIdx.x;
    if(i < PREP_S0){
        int n = i/KP0, k = i - n*KP0;
        hb[i] = (k < KIN) ? f2bf(h[n*KIN + k]) : (u16)0;
        return;
    }
    i -= PREP_S0;
    if(i < PREP_S1){                       // W0[h][k][c] -> wt0[h][c][KP0]
        int k = i % KP0; int c = (i/KP0) % HD; int hh = i/(KP0*HD);
        wt0[i] = (k < KIN) ? f2bf(W0[(hh*KIN + k)*HD + c]) : (u16)0;
        return;
    }
    i -= PREP_S1;
    if(i < PREP_S2){                       // Wr[h][k][c] -> wt1[h][c][HD]
        int k = i % HD; int c = (i/HD) % HD; int hh = i/(HD*HD);
        wt1[i] = f2bf(Wr[(hh*HD + k)*HD + c]);
        return;
    }
    i -= PREP_S2;
    if(i < NN){ counts[i] = 0; return; }
    i -= NN;
    if(i < 2048) bnstat[i] = 0.f;
}

// ---- CSR build -------------------------------------------------------------
__global__ void k_hist(const int* __restrict__ dst, int* __restrict__ counts){
    int e = blockIdx.x*256 + threadIdx.x;
    if(e < NE) atomicAdd(&counts[dst[e]], 1);
}

__global__ void k_scan1(const int* __restrict__ counts, int* __restrict__ rowptr,
                        int* __restrict__ tsum){
    __shared__ int wsum[16];
    int tx = threadIdx.x, lane = tx & 63, wid = tx >> 6;
    int i = blockIdx.x*1024 + tx;
    int v = (i < NN) ? counts[i] : 0;
    int s = v;
    #pragma unroll
    for(int d = 1; d < 64; d <<= 1){ int o = __shfl_up(s, d); if(lane >= d) s += o; }
    if(lane == 63) wsum[wid] = s;
    __syncthreads();
    int woff = 0, total = 0;
    #pragma unroll
    for(int w_ = 0; w_ < 16; ++w_){ int sw = wsum[w_]; total += sw; if(w_ < wid) woff += sw; }
    if(i < NN) rowptr[i] = woff + s - v;     // tile-local exclusive
    if(tx == 0) tsum[blockIdx.x] = total;
}

__global__ void k_scan3(int* __restrict__ rowptr, const int* __restrict__ tsum,
                        int* __restrict__ cursor){
    __shared__ int s_off;
    int tx = threadIdx.x;
    if(tx < 64){
        int v = (tx < SCAN_B && tx < (int)blockIdx.x) ? tsum[tx] : 0;
        #pragma unroll
        for(int d = 32; d > 0; d >>= 1) v += __shfl_xor(v, d);
        if(tx == 0) s_off = v;
    }
    __syncthreads();
    int i = blockIdx.x*1024 + tx;
    if(i < NN){
        int val = rowptr[i] + s_off;
        rowptr[i] = val;
        cursor[i] = val;
    }
    if(blockIdx.x == 0 && tx == 0) rowptr[NN] = NE;
}

__global__ void k_scatter(const int* __restrict__ src, const int* __restrict__ dst,
                          int* __restrict__ cursor, int* __restrict__ srcs){
    int e = blockIdx.x*256 + threadIdx.x;
    if(e >= NE) return;
    int d = dst[e];
    int p = atomicAdd(&cursor[d], 1);
    srcs[p] = src[e];
}

// ---- z = x @ W per head via MFMA; z layout [h][n][c] (r11 verbatim) --------
template<int KP>
__global__ void k_gemm_mfma(const u16* __restrict__ xb, const u16* __restrict__ wt,
                            u16* __restrict__ z){
    int h = blockIdx.y;
    int tx = threadIdx.x, lane = tx & 63, w = tx >> 6;
    int n0 = blockIdx.x*32 + (w >> 1)*16;
    int c0 = (w & 1)*64;
    int r16 = lane & 15, kg = lane >> 4;
    const u16* ap = xb + (size_t)(n0 + r16)*KP + kg*8;
    const u16* bp = wt + ((size_t)h*HD + c0 + r16)*KP + kg*8;
    f32x4 acc0 = {0.f,0.f,0.f,0.f}, acc1 = {0.f,0.f,0.f,0.f};
    f32x4 acc2 = {0.f,0.f,0.f,0.f}, acc3 = {0.f,0.f,0.f,0.f};
    #pragma unroll
    for(int k0 = 0; k0 < KP; k0 += 32){
        bf16x8 av = *(const bf16x8*)(ap + k0);
        bf16x8 b0 = *(const bf16x8*)(bp + k0);
        bf16x8 b1 = *(const bf16x8*)(bp + 16*KP + k0);
        bf16x8 b2 = *(const bf16x8*)(bp + 32*KP + k0);
        bf16x8 b3 = *(const bf16x8*)(bp + 48*KP + k0);
        acc0 = __builtin_amdgcn_mfma_f32_16x16x32_bf16(av, b0, acc0, 0, 0, 0);
        acc1 = __builtin_amdgcn_mfma_f32_16x16x32_bf16(av, b1, acc1, 0, 0, 0);
        acc2 = __builtin_amdgcn_mfma_f32_16x16x32_bf16(av, b2, acc2, 0, 0, 0);
        acc3 = __builtin_amdgcn_mfma_f32_16x16x32_bf16(av, b3, acc3, 0, 0, 0);
    }
    int nbase = n0 + kg*4;
    u16* zp = z + ((size_t)h*NN + nbase)*HD + c0 + r16;
    #pragma unroll
    for(int reg = 0; reg < 4; ++reg){
        u16* q = zp + (size_t)reg*HD;
        q[0]  = f2bf(acc0[reg]);
        q[16] = f2bf(acc1[reg]);
        q[32] = f2bf(acc2[reg]);
        q[48] = f2bf(acc3[reg]);
    }
}

// ---- per-node attention dot products, vectorized (G13) ---------------------
// grid (NN/16, NH), 256 thr = 4 waves; wave = 4 nodes. Lane: sub=l>>4 (node),
// cg=l&15 (channels cg*8..+7). uint4 load = 1KB contiguous per wave.
__global__ void k_dots(const u16* __restrict__ z, const float* __restrict__ attj,
                       float* __restrict__ es, float* __restrict__ ed){
    int tx = threadIdx.x, lane = tx & 63, w = tx >> 6;
    int h = blockIdx.y;
    int n = blockIdx.x*16 + w*4 + (lane >> 4);
    int cg = lane & 15;
    int ch = cg*8;
    uint4 v = *(const uint4*)(z + ((size_t)h*NN + n)*HD + ch);
    float zv[8];
    zv[0] = bflo(v.x); zv[1] = bfhi(v.x);
    zv[2] = bflo(v.y); zv[3] = bfhi(v.y);
    zv[4] = bflo(v.z); zv[5] = bfhi(v.z);
    zv[6] = bflo(v.w); zv[7] = bfhi(v.w);
    const float* ah = attj + h*2*HD;
    float ps = 0.f, pd = 0.f;
    #pragma unroll
    for(int k = 0; k < 8; ++k){
        ps += zv[k]*ah[ch+k];
        pd += zv[k]*ah[HD+ch+k];
    }
    #pragma unroll
    for(int d = 1; d < 16; d <<= 1){ ps += __shfl_xor(ps, d); pd += __shfl_xor(pd, d); }
    if(cg == 0){ es[(size_t)h*NN + n] = ps; ed[(size_t)h*NN + n] = pd; }
}

// ---- fused edge-logit + segment softmax + aggregation + relu (r11 verbatim) -
__global__ void k_aggregate(const int* __restrict__ rowptr, const int* __restrict__ srcs,
                            const float* __restrict__ es, const float* __restrict__ ed,
                            const u16* __restrict__ z, u16* __restrict__ r){
    int tx = threadIdx.x, lane = tx & 63, w = tx >> 6;
    int n = blockIdx.x*4 + w;
    int h = blockIdx.y;
    int p0 = rowptr[n], p1 = rowptr[n+1];
    int eslot = lane >> 4;       // 0..3
    int cidx  = lane & 15;       // 8 channels: cidx*8 .. +7
    const float* esh = es + (size_t)h*NN;
    const u16*   zh  = z  + (size_t)h*NN*HD;
    float edn = ed[(size_t)h*NN + n];
    float ssum = 0.f;
    f32x2 acc[4];
    #pragma unroll
    for(int k = 0; k < 4; ++k) acc[k] = (f32x2){0.f, 0.f};

    for(int base = p0; base < p1; base += 64){
        int p = base + lane;
        int sn = 0; float ex = 0.f;
        if(p < p1){
            sn = srcs[p];
            float e = esh[sn] + edn;
            e = e >= 0.f ? e : 0.01f*e;          // leaky_relu slope 0.01
            ex = __expf(e);
        }
        ssum += ex;
        int cnt = min(64, p1 - base);
        int niter = (cnt + 7) >> 3;              // 8 edges per iteration
        for(int i = 0; i < niter; ++i){
            int e0 = i*8 + eslot;                // <= 59
            int e1 = e0 + 4;                     // <= 63 (ex==0 past cnt)
            float a0 = __shfl(ex, e0);
            int   s0 = __shfl(sn, e0);
            float a1 = __shfl(ex, e1);
            int   s1 = __shfl(sn, e1);
            uint4 v0 = *(const uint4*)(zh + (size_t)s0*HD + cidx*8);
            uint4 v1 = *(const uint4*)(zh + (size_t)s1*HD + cidx*8);
            f32x2 t;
            t.x = bflo(v0.x); t.y = bfhi(v0.x); acc[0] += a0*t;
            t.x = bflo(v0.y); t.y = bfhi(v0.y); acc[1] += a0*t;
            t.x = bflo(v0.z); t.y = bfhi(v0.z); acc[2] += a0*t;
            t.x = bflo(v0.w); t.y = bfhi(v0.w); acc[3] += a0*t;
            t.x = bflo(v1.x); t.y = bfhi(v1.x); acc[0] += a1*t;
            t.x = bflo(v1.y); t.y = bfhi(v1.y); acc[1] += a1*t;
            t.x = bflo(v1.z); t.y = bfhi(v1.z); acc[2] += a1*t;
            t.x = bflo(v1.w); t.y = bfhi(v1.w); acc[3] += a1*t;
        }
    }
    float c01[8];
    #pragma unroll
    for(int k = 0; k < 4; ++k){
        float a0 = acc[k].x, a1 = acc[k].y;
        a0 += __shfl_xor(a0, 16); a0 += __shfl_xor(a0, 32);
        a1 += __shfl_xor(a1, 16); a1 += __shfl_xor(a1, 32);
        c01[k*2] = a0; c01[k*2+1] = a1;
    }
    #pragma unroll
    for(int d = 32; d > 0; d >>= 1) ssum += __shfl_xor(ssum, d);
    float inv = (ssum > 0.f) ? 1.f/ssum : 0.f;
    if(eslot == 0){
        uint4 o;
        o.x = pack2(fmaxf(c01[0]*inv, 0.f), fmaxf(c01[1]*inv, 0.f));
        o.y = pack2(fmaxf(c01[2]*inv, 0.f), fmaxf(c01[3]*inv, 0.f));
        o.z = pack2(fmaxf(c01[4]*inv, 0.f), fmaxf(c01[5]*inv, 0.f));
        o.w = pack2(fmaxf(c01[6]*inv, 0.f), fmaxf(c01[7]*inv, 0.f));
        *(uint4*)(r + ((size_t)n*NH + h)*HD + cidx*8) = o;
    }
}

// ---- BatchNorm stats, vectorized (G13) -------------------------------------
// grid 125, block 256 = 4 waves. Wave = full 512-ch row (lane = 8 channels),
// 40 rows per thread (rows nbeg + w + 4t). LDS-combine 4 waves, then
// 1024 atomics/block (125-way contention, same as before).
__global__ void k_bnreduce(const u16* __restrict__ r, float* __restrict__ bnsum,
                           float* __restrict__ bnsqs){
    __shared__ float sm[4][512], sm2[4][512];
    int tx = threadIdx.x, lane = tx & 63, w = tx >> 6;
    int nbeg = blockIdx.x * 160;
    const u16* rp = r + (size_t)(nbeg + w)*512 + lane*8;
    float s[8], s2[8];
    #pragma unroll
    for(int k = 0; k < 8; ++k){ s[k] = 0.f; s2[k] = 0.f; }
    for(int t = 0; t < 40; ++t){
        uint4 v = *(const uint4*)(rp + (size_t)t*4*512);
        float zv[8];
        zv[0] = bflo(v.x); zv[1] = bfhi(v.x);
        zv[2] = bflo(v.y); zv[3] = bfhi(v.y);
        zv[4] = bflo(v.z); zv[5] = bfhi(v.z);
        zv[6] = bflo(v.w); zv[7] = bfhi(v.w);
        #pragma unroll
        for(int k = 0; k < 8; ++k){ s[k] += zv[k]; s2[k] += zv[k]*zv[k]; }
    }
    #pragma unroll
    for(int k = 0; k < 8; ++k){
        sm[w][lane*8 + k] = s[k];
        sm2[w][lane*8 + k] = s2[k];
    }
    __syncthreads();
    #pragma unroll
    for(int c = tx; c < 512; c += 256){
        float S  = (sm[0][c] + sm[1][c]) + (sm[2][c] + sm[3][c]);
        float S2 = (sm2[0][c] + sm2[1][c]) + (sm2[2][c] + sm2[3][c]);
        atomicAdd(&bnsum[c], S);
        atomicAdd(&bnsqs[c], S2);
    }
}

// ---- BN finalize + apply + head softmax mix, vectorized (G13) --------------
// grid NN/4, block 256 = 4 waves; wave = node. Lane: h=l>>4, cg=l&15 ->
// 8 channels of head h. uint4 load = 1KB contiguous per wave. Head exchange
// via shfl_xor 16/32/48 (pairwise sums bit-identical across lanes).
__global__ void k_headmix(const u16* __restrict__ r, const float* __restrict__ bnsum,
                          const float* __restrict__ bnsqs, const float* __restrict__ gamma,
                          const float* __restrict__ beta, const float* __restrict__ ow,
                          u16* __restrict__ x){
    __shared__ float sinv[512], sshift[512];
    int tx = threadIdx.x;
    #pragma unroll
    for(int c = tx; c < 512; c += 256){
        float mean = bnsum[c] * (1.f/NN);
        float var  = bnsqs[c] * (1.f/NN) - mean*mean;
        float iv = gamma[c] * rsqrtf(var + BN_EPS);
        sinv[c] = iv;
        sshift[c] = beta[c] - mean*iv;
    }
    __syncthreads();
    int lane = tx & 63, w = tx >> 6;
    int n = blockIdx.x*4 + w;
    int h = lane >> 4;
    int ch = (lane & 15)*8;           // channel base within head
    int c0 = h*HD + ch;               // channel base within 512
    uint4 rv = *(const uint4*)(r + (size_t)n*512 + c0);
    float v[8];
    v[0] = bflo(rv.x); v[1] = bfhi(rv.x);
    v[2] = bflo(rv.y); v[3] = bfhi(rv.y);
    v[4] = bflo(rv.z); v[5] = bfhi(rv.z);
    v[6] = bflo(rv.w); v[7] = bfhi(rv.w);
    float p = 0.f;
    #pragma unroll
    for(int k = 0; k < 8; ++k){
        v[k] = v[k]*sinv[c0+k] + sshift[c0+k];
        p += v[k]*ow[ch+k];
    }
    #pragma unroll
    for(int d = 1; d < 16; d <<= 1) p += __shfl_xor(p, d);
    // exchange head scores: {p, p^16, p^32, p^48} = the 4 heads' scores
    float q1 = __shfl_xor(p, 16);
    float q2 = __shfl_xor(p, 32);
    float q3 = __shfl_xor(p, 48);
    float m = fmaxf(fmaxf(p, q1), fmaxf(q2, q3));
    float e0 = __expf(p - m), e1 = __expf(q1 - m);
    float e2 = __expf(q2 - m), e3 = __expf(q3 - m);
    float is = 1.f/((e0 + e1) + (e2 + e3));     // bit-identical across lane group
    float t[8];
    #pragma unroll
    for(int k = 0; k < 8; ++k) t[k] = e0*v[k];  // e0 = this lane's head weight
    #pragma unroll
    for(int k = 0; k < 8; ++k){
        t[k] += __shfl_xor(t[k], 16);
        t[k] += __shfl_xor(t[k], 32);           // sum over 4 heads, same ch
    }
    if(h == 0){
        uint4 o;
        o.x = pack2(t[0]*is, t[1]*is);
        o.y = pack2(t[2]*is, t[3]*is);
        o.z = pack2(t[4]*is, t[5]*is);
        o.w = pack2(t[6]*is, t[7]*is);
        *(uint4*)(x + (size_t)n*HD + ch) = o;
    }
}

// ---- per-graph mean (r11 verbatim) ------------------------------------------
__global__ void k_gmean(const int* __restrict__ gid, const u16* __restrict__ x,
                        float* __restrict__ out){
    int g = blockIdx.x;
    int tx = threadIdx.x, lane = tx & 63, w = tx >> 6;
    int lo = 0, hi = NN;
    while(lo < hi){ int mid = (lo + hi) >> 1; if(gid[mid] < g) lo = mid + 1; else hi = mid; }
    int start = lo;
    hi = NN;
    while(lo < hi){ int mid = (lo + hi) >> 1; if(gid[mid] < g + 1) lo = mid + 1; else hi = mid; }
    int end = lo;
    float a0 = 0.f, a1 = 0.f;
    for(int n = start + w; n < end; n += 4){
        u32 zz = *(const u32*)(x + (size_t)n*HD + lane*2);
        a0 += bflo(zz);
        a1 += bfhi(zz);
    }
    __shared__ float sm[4][HD];
    sm[w][lane*2]     = a0;
    sm[w][lane*2 + 1] = a1;
    __syncthreads();
    if(tx < HD){
        float s = sm[0][tx] + sm[1][tx] + sm[2][tx] + sm[3][tx];
        float cnt = (float)(end - start);
        out[g*HD + tx] = s / fmaxf(cnt, 1.f);
    }
}

extern "C" void kernel_launch(void* const* d_in, const int* in_sizes, int n_in,
                              void* d_out, int out_size, void* d_ws, size_t ws_size,
                              hipStream_t stream){
    const float* h     = (const float*)d_in[0];
    const int*   src   = (const int*)  d_in[1];
    const int*   dst   = (const int*)  d_in[2];
    const int*   gid   = (const int*)  d_in[3];
    const float* W0    = (const float*)d_in[4];
    const float* Wr    = (const float*)d_in[5];
    const float* att   = (const float*)d_in[6];
    const float* gamma = (const float*)d_in[7];
    const float* beta  = (const float*)d_in[8];
    const float* ow    = (const float*)d_in[9];

    char* p = (char*)d_ws;
    auto alloc = [&](size_t bytes) -> void* {
        void* q = (void*)p;
        p += (bytes + 255) & ~(size_t)255;
        return q;
    };
    u16*   z      = (u16*)  alloc((size_t)NN*NH*HD*2);   // 20.5 MB, [h][n][c]
    u16*   r      = (u16*)  alloc((size_t)NN*NH*HD*2);   // 20.5 MB, [n][h][c]
    u16*   x      = (u16*)  alloc((size_t)NN*HD*2);      // 5.1 MB
    u16*   hb     = (u16*)  alloc((size_t)NN*KP0*2);     // 3.8 MB
    u16*   wt0    = (u16*)  alloc((size_t)NH*HD*KP0*2);
    u16*   wt1    = (u16*)  alloc((size_t)NH*HD*HD*2);
    float* es     = (float*)alloc((size_t)NN*NH*4);      // [h][n]
    float* ed     = (float*)alloc((size_t)NN*NH*4);      // [h][n]
    int*   counts = (int*)  alloc((size_t)NN*4);
    int*   rowptr = (int*)  alloc((size_t)(NN+1)*4);
    int*   cursor = (int*)  alloc((size_t)NN*4);
    int*   srcs   = (int*)  alloc((size_t)NE*4);
    int*   tsum   = (int*)  alloc((size_t)SCAN_B*4);
    float* bnstat = (float*)alloc(2048*4);               // [layer][sum512|sqs512]

    // fused prep: conversions + zero counts + zero bnstat (both layers)
    k_prep<<<(PREP_TOT+255)/256, 256, 0, stream>>>(h, W0, Wr, hb, wt0, wt1,
                                                   counts, bnstat);

    // CSR build (graph is identical both layers)
    k_hist   <<<(NE+255)/256, 256, 0, stream>>>(dst, counts);
    k_scan1  <<<SCAN_B, 1024, 0, stream>>>(counts, rowptr, tsum);
    k_scan3  <<<SCAN_B, 1024, 0, stream>>>(rowptr, tsum, cursor);
    k_scatter<<<(NE+255)/256, 256, 0, stream>>>(src, dst, cursor, srcs);

    for(int j = 0; j < 2; ++j){
        const float* attj = att + j*NH*2*HD;
        if(j == 0) k_gemm_mfma<KP0><<<dim3(NN/32, NH), 256, 0, stream>>>(hb, wt0, z);
        else       k_gemm_mfma<HD> <<<dim3(NN/32, NH), 256, 0, stream>>>(x,  wt1, z);

        k_dots     <<<dim3(NN/16, NH), 256, 0, stream>>>(z, attj, es, ed);
        k_aggregate<<<dim3(NN/4, NH), 256, 0, stream>>>(rowptr, srcs, es, ed, z, r);

        k_bnreduce <<<125, 256, 0, stream>>>(r, bnstat + j*1024, bnstat + j*1024 + 512);
        k_headmix  <<<NN/4, 256, 0, stream>>>(r, bnstat + j*1024, bnstat + j*1024 + 512,
                                              gamma + j*512, beta + j*512, ow + j*HD, x);
    }

    k_gmean<<<NG, 256, 0, stream>>>(gid, x, (float*)d_out);
}